// Round 1
// baseline (1185.984 us; speedup 1.0000x reference)
//
#include <hip/hip_runtime.h>
#include <hip/hip_bf16.h>
#include <math.h>

#define N_NODES 100000
#define N_EDGES 1600000

__device__ __forceinline__ float sigmoidf_(float x) { return 1.0f / (1.0f + expf(-x)); }

// ---------------- LSTM: 64 independent row-recurrences, 5 steps ----------------
// xb_1 = init_w.T, h0=c0=0; steps 2..5: xb=h => gates = h @ (W_ih+W_hh)^T.
// Block r handles row r. Output h5[r][k] (w5[k][j] = h5[j][k]).
__global__ __launch_bounds__(256) void lstm_kernel(
    const float* __restrict__ init_w, const float* __restrict__ w_ih,
    const float* __restrict__ w_hh, const float* __restrict__ b_ih,
    const float* __restrict__ b_hh, float* __restrict__ h_out)
{
    __shared__ float wsum[256 * 65];   // row-stride 65: bank = (g+k)%32 -> 2-way (free)
    __shared__ float hst[64];
    __shared__ float cst[64];
    __shared__ float gts[256];
    const int t = threadIdx.x;
    const int r = blockIdx.x;

    for (int i = t; i < 256 * 64; i += 256) {
        int g = i >> 6, k = i & 63;
        wsum[g * 65 + k] = w_ih[i] + w_hh[i];
    }
    if (t < 64) hst[t] = init_w[t * 64 + r];   // xb[k] = init_w[k][r]
    __syncthreads();

    // step 1: gates = xb @ W_ih^T + b (h=0, c=0)
    {
        float acc = b_ih[t] + b_hh[t];
        for (int k = 0; k < 64; ++k) acc += hst[k] * w_ih[t * 64 + k];
        gts[t] = acc;
    }
    __syncthreads();
    if (t < 64) {
        float ig = sigmoidf_(gts[t]);
        float gg = tanhf(gts[128 + t]);
        float og = sigmoidf_(gts[192 + t]);
        float c = ig * gg;                 // f*c0 = 0
        float h = og * tanhf(c);
        cst[t] = c; hst[t] = h;
    }
    __syncthreads();

    for (int step = 1; step < 5; ++step) {
        float acc = b_ih[t] + b_hh[t];
        for (int k = 0; k < 64; ++k) acc += hst[k] * wsum[t * 65 + k];
        gts[t] = acc;
        __syncthreads();
        if (t < 64) {
            float ig = sigmoidf_(gts[t]);
            float fg = sigmoidf_(gts[64 + t]);
            float gg = tanhf(gts[128 + t]);
            float og = sigmoidf_(gts[192 + t]);
            float c = fg * cst[t] + ig * gg;
            float h = og * tanhf(c);
            cst[t] = c; hst[t] = h;
        }
        __syncthreads();
    }
    if (t < 64) h_out[r * 64 + t] = hst[t];
}

// ---------------- degree count over col (self-loop added analytically) ----------------
__global__ void deg_kernel(const int* __restrict__ col, int* __restrict__ cnt, int nE)
{
    int i = blockIdx.x * blockDim.x + threadIdx.x;
    int stride = gridDim.x * blockDim.x;
    for (; i < nE; i += stride) atomicAdd(&cnt[col[i]], 1);
}

__global__ void dinv_kernel(const int* __restrict__ cnt, float* __restrict__ dinv, int n)
{
    int i = blockIdx.x * blockDim.x + threadIdx.x;
    int stride = gridDim.x * blockDim.x;
    for (; i < n; i += stride) dinv[i] = rsqrtf((float)(cnt[i] + 1));   // +1 self-loop
}

// ---------------- exclusive prefix sum (single block, 4 elems/thread) ----------------
__global__ __launch_bounds__(1024) void scan_kernel(
    const int* __restrict__ cnt, int* __restrict__ offs, int n)
{
    __shared__ int wsums[16];
    __shared__ int carry_s;
    const int tid = threadIdx.x, lane = tid & 63, wid = tid >> 6;
    if (tid == 0) carry_s = 0;
    __syncthreads();
    for (int base = 0; base < n; base += 4096) {
        int i0 = base + tid * 4;
        int v0 = 0, v1 = 0, v2 = 0, v3 = 0;
        if (i0 + 3 < n) { int4 v = *(const int4*)(cnt + i0); v0 = v.x; v1 = v.y; v2 = v.z; v3 = v.w; }
        else {
            if (i0 < n)     v0 = cnt[i0];
            if (i0 + 1 < n) v1 = cnt[i0 + 1];
            if (i0 + 2 < n) v2 = cnt[i0 + 2];
            if (i0 + 3 < n) v3 = cnt[i0 + 3];
        }
        int tot = v0 + v1 + v2 + v3;
        int s = tot;
        #pragma unroll
        for (int d = 1; d < 64; d <<= 1) { int u = __shfl_up(s, d, 64); if (lane >= d) s += u; }
        if (lane == 63) wsums[wid] = s;
        __syncthreads();
        if (tid == 0) {
            int run = carry_s;
            #pragma unroll
            for (int w = 0; w < 16; ++w) { int u = wsums[w]; wsums[w] = run; run += u; }
            carry_s = run;
        }
        __syncthreads();
        int ex = s - tot + wsums[wid];
        if (i0 < n)     offs[i0]     = ex;
        if (i0 + 1 < n) offs[i0 + 1] = ex + v0;
        if (i0 + 2 < n) offs[i0 + 2] = ex + v0 + v1;
        if (i0 + 3 < n) offs[i0 + 3] = ex + v0 + v1 + v2;
        __syncthreads();
    }
}

// ---------------- CSR fill: csr[offs[c] + pos] = row ----------------
__global__ void fill_kernel(const int* __restrict__ row, const int* __restrict__ col,
                            const int* __restrict__ offs, int* __restrict__ fill,
                            int* __restrict__ csr, int nE)
{
    int i = blockIdx.x * blockDim.x + threadIdx.x;
    int stride = gridDim.x * blockDim.x;
    for (; i < nE; i += stride) {
        int c = col[i];
        int pos = atomicAdd(&fill[c], 1);
        csr[offs[c] + pos] = row[i];
    }
}

// ---------------- y[n][j] = dinv[n] * sum_k xs4[n][k] * h5[j][k] ----------------
__global__ __launch_bounds__(256) void xw_kernel(
    const float* __restrict__ x4, const float* __restrict__ h5,
    const float* __restrict__ dinv, float* __restrict__ y, int n)
{
    __shared__ float wlds[64 * 64];          // wlds[k][j] = h5[j][k]
    const int t = threadIdx.x;
    for (int i = t; i < 4096; i += 256) {
        int j = i >> 6, k = i & 63;
        wlds[k * 64 + j] = h5[i];
    }
    __syncthreads();
    const int lane = t & 63;
    int wv = blockIdx.x * 4 + (t >> 6);
    const int nw = gridDim.x * 4;
    for (int nd = wv; nd < n; nd += nw) {
        float xv = x4[(size_t)nd * 64 + lane];
        float acc = 0.f;
        #pragma unroll
        for (int k = 0; k < 64; ++k) {
            float xk = __shfl(xv, k, 64);
            acc += xk * wlds[k * 64 + lane];   // bank (j%32): 2-way, free
        }
        y[(size_t)nd * 64 + lane] = acc * dinv[nd];
    }
}

// ---------------- x_last[c] = relu(dinv[c] * (y[c] + sum_in-edges y[r])) ----------------
__global__ __launch_bounds__(256) void gather_kernel(
    const int* __restrict__ offs, const int* __restrict__ cnt,
    const int* __restrict__ csr, const float* __restrict__ y,
    const float* __restrict__ dinv, float* __restrict__ xl, int n)
{
    const int lane = threadIdx.x & 63;
    int wv = blockIdx.x * 4 + (threadIdx.x >> 6);
    const int nw = gridDim.x * 4;
    for (int c = wv; c < n; c += nw) {
        float acc = y[(size_t)c * 64 + lane];           // self-loop term
        int beg = offs[c], num = cnt[c];
        for (int p = 0; p < num; ++p) {
            int r = csr[beg + p];                        // wave-uniform
            acc += y[(size_t)r * 64 + lane];             // 256B coalesced gather
        }
        xl[(size_t)c * 64 + lane] = fmaxf(acc * dinv[c], 0.0f);
    }
}

// ---------------- edge MLP: logits[e] = relu([h_src|h_dst|ea] @ W1 + b1) @ W2 + b2 ----
__global__ __launch_bounds__(256) void mlp_kernel(
    const float* __restrict__ xl, const int* __restrict__ ei,
    const float* __restrict__ ea, const float* __restrict__ w1,
    const float* __restrict__ b1, const float* __restrict__ w2,
    const float* __restrict__ b2, float* __restrict__ out, int nE)
{
    __shared__ float4 W1s[144 * 16];
    __shared__ float b1s[64], W2s[64];
    __shared__ float b2s;
    const int t = threadIdx.x;
    for (int i = t; i < 144 * 16; i += 256) W1s[i] = ((const float4*)w1)[i];
    if (t < 64) { b1s[t] = b1[t]; W2s[t] = w2[t]; }
    if (t == 0) b2s = b2[0];
    __syncthreads();

    int e = blockIdx.x * 256 + t;
    if (e >= nE) return;
    const int src = ei[e], dst = ei[nE + e];

    float acc[64];
    #pragma unroll
    for (int j = 0; j < 64; ++j) acc[j] = b1s[j];

    const float* ps = xl + (size_t)src * 64;
    #pragma unroll 2
    for (int k = 0; k < 64; ++k) {
        float xk = ps[k];
        #pragma unroll
        for (int j4 = 0; j4 < 16; ++j4) {
            float4 w = W1s[k * 16 + j4];                 // LDS broadcast
            acc[j4 * 4 + 0] += xk * w.x; acc[j4 * 4 + 1] += xk * w.y;
            acc[j4 * 4 + 2] += xk * w.z; acc[j4 * 4 + 3] += xk * w.w;
        }
    }
    const float* pd = xl + (size_t)dst * 64;
    #pragma unroll 2
    for (int k = 0; k < 64; ++k) {
        float xk = pd[k];
        #pragma unroll
        for (int j4 = 0; j4 < 16; ++j4) {
            float4 w = W1s[(64 + k) * 16 + j4];
            acc[j4 * 4 + 0] += xk * w.x; acc[j4 * 4 + 1] += xk * w.y;
            acc[j4 * 4 + 2] += xk * w.z; acc[j4 * 4 + 3] += xk * w.w;
        }
    }
    const float4* pe = (const float4*)(ea + (size_t)e * 16);
    #pragma unroll
    for (int k4 = 0; k4 < 4; ++k4) {
        float4 xv = pe[k4];
        float xs_[4] = { xv.x, xv.y, xv.z, xv.w };
        #pragma unroll
        for (int c = 0; c < 4; ++c) {
            float xk = xs_[c];
            int k = k4 * 4 + c;
            #pragma unroll
            for (int j4 = 0; j4 < 16; ++j4) {
                float4 w = W1s[(128 + k) * 16 + j4];
                acc[j4 * 4 + 0] += xk * w.x; acc[j4 * 4 + 1] += xk * w.y;
                acc[j4 * 4 + 2] += xk * w.z; acc[j4 * 4 + 3] += xk * w.w;
            }
        }
    }
    float sres = b2s;
    #pragma unroll
    for (int j = 0; j < 64; ++j) sres += fmaxf(acc[j], 0.f) * W2s[j];
    out[e] = sres;                                       // coalesced
}

extern "C" void kernel_launch(void* const* d_in, const int* in_sizes, int n_in,
                              void* d_out, int out_size, void* d_ws, size_t ws_size,
                              hipStream_t stream)
{
    const float* xs     = (const float*)d_in[0];
    const int*   ei     = (const int*)  d_in[1];
    const float* ea     = (const float*)d_in[2];
    const float* init_w = (const float*)d_in[3];
    const float* w_ih   = (const float*)d_in[4];
    const float* w_hh   = (const float*)d_in[5];
    const float* b_ih   = (const float*)d_in[6];
    const float* b_hh   = (const float*)d_in[7];
    const float* w1     = (const float*)d_in[8];
    const float* b1     = (const float*)d_in[9];
    const float* w2     = (const float*)d_in[10];
    const float* b2     = (const float*)d_in[11];
    float* out = (float*)d_out;

    char* ws = (char*)d_ws;
    size_t off = 0;
    auto alloc = [&](size_t bytes) {
        void* p = ws + off;
        off = (off + bytes + 255) & ~(size_t)255;
        return p;
    };
    float* h5   = (float*)alloc(64 * 64 * sizeof(float));
    int*   deg  = (int*)  alloc((size_t)N_NODES * sizeof(int));
    int*   fill = (int*)  alloc((size_t)N_NODES * sizeof(int));
    float* dinv = (float*)alloc((size_t)N_NODES * sizeof(float));
    int*   offs = (int*)  alloc((size_t)N_NODES * sizeof(int));
    int*   csr  = (int*)  alloc((size_t)N_EDGES * sizeof(int));
    float* y    = (float*)alloc((size_t)N_NODES * 64 * sizeof(float));
    float* xl   = (float*)alloc((size_t)N_NODES * 64 * sizeof(float));

    hipMemsetAsync(deg, 0, (size_t)N_NODES * sizeof(int), stream);
    hipMemsetAsync(fill, 0, (size_t)N_NODES * sizeof(int), stream);

    lstm_kernel<<<64, 256, 0, stream>>>(init_w, w_ih, w_hh, b_ih, b_hh, h5);
    deg_kernel<<<1024, 256, 0, stream>>>(ei + N_EDGES, deg, N_EDGES);
    dinv_kernel<<<512, 256, 0, stream>>>(deg, dinv, N_NODES);
    scan_kernel<<<1, 1024, 0, stream>>>(deg, offs, N_NODES);
    fill_kernel<<<1024, 256, 0, stream>>>(ei, ei + N_EDGES, offs, fill, csr, N_EDGES);

    const float* x4 = xs + (size_t)4 * N_NODES * 64;     // only t=4 slab is live
    xw_kernel<<<2048, 256, 0, stream>>>(x4, h5, dinv, y, N_NODES);
    gather_kernel<<<2048, 256, 0, stream>>>(offs, deg, csr, y, dinv, xl, N_NODES);
    mlp_kernel<<<(N_EDGES + 255) / 256, 256, 0, stream>>>(xl, ei, ea, w1, b1, w2, b2, out, N_EDGES);
}

// Round 2
// 692.364 us; speedup vs baseline: 1.7129x; 1.7129x over previous
//
#include <hip/hip_runtime.h>
#include <hip/hip_bf16.h>
#include <math.h>

#define N_NODES 100000
#define N_EDGES 1600000

#define KP 168   // LDS row stride in bf16 elems (336 B = 84 dw = 20 mod 32 -> bank-spread)
#define KU 160   // padded K actually fed to MFMA (144 real + 16 zero)

typedef __attribute__((ext_vector_type(8))) short bf16x8;
typedef __attribute__((ext_vector_type(4))) float f32x4;

__device__ __forceinline__ float sigmoidf_(float x) { return 1.0f / (1.0f + expf(-x)); }
__device__ __forceinline__ unsigned short f2b(float x) {
    __hip_bfloat16 b = __float2bfloat16(x);
    return *(unsigned short*)&b;
}
__device__ __forceinline__ float b2f(unsigned short u) {
    __hip_bfloat16 b = *(__hip_bfloat16*)&u;
    return __bfloat162float(b);
}

// ---------------- LSTM: 64 independent row-recurrences, 5 steps ----------------
__global__ __launch_bounds__(256) void lstm_kernel(
    const float* __restrict__ init_w, const float* __restrict__ w_ih,
    const float* __restrict__ w_hh, const float* __restrict__ b_ih,
    const float* __restrict__ b_hh, float* __restrict__ h_out)
{
    __shared__ float wsum[256 * 65];
    __shared__ float hst[64];
    __shared__ float cst[64];
    __shared__ float gts[256];
    const int t = threadIdx.x;
    const int r = blockIdx.x;

    for (int i = t; i < 256 * 64; i += 256) {
        int g = i >> 6, k = i & 63;
        wsum[g * 65 + k] = w_ih[i] + w_hh[i];
    }
    if (t < 64) hst[t] = init_w[t * 64 + r];
    __syncthreads();

    {
        float acc = b_ih[t] + b_hh[t];
        for (int k = 0; k < 64; ++k) acc += hst[k] * w_ih[t * 64 + k];
        gts[t] = acc;
    }
    __syncthreads();
    if (t < 64) {
        float ig = sigmoidf_(gts[t]);
        float gg = tanhf(gts[128 + t]);
        float og = sigmoidf_(gts[192 + t]);
        float c = ig * gg;
        float h = og * tanhf(c);
        cst[t] = c; hst[t] = h;
    }
    __syncthreads();

    for (int step = 1; step < 5; ++step) {
        float acc = b_ih[t] + b_hh[t];
        for (int k = 0; k < 64; ++k) acc += hst[k] * wsum[t * 65 + k];
        gts[t] = acc;
        __syncthreads();
        if (t < 64) {
            float ig = sigmoidf_(gts[t]);
            float fg = sigmoidf_(gts[64 + t]);
            float gg = tanhf(gts[128 + t]);
            float og = sigmoidf_(gts[192 + t]);
            float c = fg * cst[t] + ig * gg;
            float h = og * tanhf(c);
            cst[t] = c; hst[t] = h;
        }
        __syncthreads();
    }
    if (t < 64) h_out[r * 64 + t] = hst[t];
}

// ---------------- degree count over col (self-loop added analytically) ----------------
__global__ void deg_kernel(const int* __restrict__ col, int* __restrict__ cnt, int nE)
{
    int i = blockIdx.x * blockDim.x + threadIdx.x;
    int stride = gridDim.x * blockDim.x;
    for (; i < nE; i += stride) atomicAdd(&cnt[col[i]], 1);
}

__global__ void dinv_kernel(const int* __restrict__ cnt, float* __restrict__ dinv, int n)
{
    int i = blockIdx.x * blockDim.x + threadIdx.x;
    int stride = gridDim.x * blockDim.x;
    for (; i < n; i += stride) dinv[i] = rsqrtf((float)(cnt[i] + 1));
}

// ---------------- exclusive prefix sum (single block) ----------------
__global__ __launch_bounds__(1024) void scan_kernel(
    const int* __restrict__ cnt, int* __restrict__ offs, int n)
{
    __shared__ int wsums[16];
    __shared__ int carry_s;
    const int tid = threadIdx.x, lane = tid & 63, wid = tid >> 6;
    if (tid == 0) carry_s = 0;
    __syncthreads();
    for (int base = 0; base < n; base += 4096) {
        int i0 = base + tid * 4;
        int v0 = 0, v1 = 0, v2 = 0, v3 = 0;
        if (i0 + 3 < n) { int4 v = *(const int4*)(cnt + i0); v0 = v.x; v1 = v.y; v2 = v.z; v3 = v.w; }
        else {
            if (i0 < n)     v0 = cnt[i0];
            if (i0 + 1 < n) v1 = cnt[i0 + 1];
            if (i0 + 2 < n) v2 = cnt[i0 + 2];
            if (i0 + 3 < n) v3 = cnt[i0 + 3];
        }
        int tot = v0 + v1 + v2 + v3;
        int s = tot;
        #pragma unroll
        for (int d = 1; d < 64; d <<= 1) { int u = __shfl_up(s, d, 64); if (lane >= d) s += u; }
        if (lane == 63) wsums[wid] = s;
        __syncthreads();
        if (tid == 0) {
            int run = carry_s;
            #pragma unroll
            for (int w = 0; w < 16; ++w) { int u = wsums[w]; wsums[w] = run; run += u; }
            carry_s = run;
        }
        __syncthreads();
        int ex = s - tot + wsums[wid];
        if (i0 < n)     offs[i0]     = ex;
        if (i0 + 1 < n) offs[i0 + 1] = ex + v0;
        if (i0 + 2 < n) offs[i0 + 2] = ex + v0 + v1;
        if (i0 + 3 < n) offs[i0 + 3] = ex + v0 + v1 + v2;
        __syncthreads();
    }
}

// ---------------- CSR fill ----------------
__global__ void fill_kernel(const int* __restrict__ row, const int* __restrict__ col,
                            const int* __restrict__ offs, int* __restrict__ fill,
                            int* __restrict__ csr, int nE)
{
    int i = blockIdx.x * blockDim.x + threadIdx.x;
    int stride = gridDim.x * blockDim.x;
    for (; i < nE; i += stride) {
        int c = col[i];
        int pos = atomicAdd(&fill[c], 1);
        csr[offs[c] + pos] = row[i];
    }
}

// ---------------- y[n][j] = dinv[n] * sum_k x4[n][k] * h5[j][k]  (bf16 out) --------
__global__ __launch_bounds__(256) void xw_kernel(
    const float* __restrict__ x4, const float* __restrict__ h5,
    const float* __restrict__ dinv, unsigned short* __restrict__ y, int n)
{
    __shared__ float wlds[64 * 64];          // wlds[k][j] = h5[j][k]
    const int t = threadIdx.x;
    for (int i = t; i < 4096; i += 256) {
        int j = i >> 6, k = i & 63;
        wlds[k * 64 + j] = h5[i];
    }
    __syncthreads();
    const int lane = t & 63;
    int wv = blockIdx.x * 4 + (t >> 6);
    const int nw = gridDim.x * 4;
    for (int nd = wv; nd < n; nd += nw) {
        float xv = x4[(size_t)nd * 64 + lane];
        float acc = 0.f;
        #pragma unroll
        for (int k = 0; k < 64; ++k) {
            float xk = __shfl(xv, k, 64);
            acc += xk * wlds[k * 64 + lane];
        }
        y[(size_t)nd * 64 + lane] = f2b(acc * dinv[nd]);
    }
}

// ---------------- xl[c] = relu(dinv[c]*(y[c] + sum_in y[r]))  (bf16 in/out) ---------
__global__ __launch_bounds__(256) void gather_kernel(
    const int* __restrict__ offs, const int* __restrict__ cnt,
    const int* __restrict__ csr, const unsigned short* __restrict__ y,
    const float* __restrict__ dinv, unsigned short* __restrict__ xl, int n)
{
    const int lane = threadIdx.x & 63;
    int wv = blockIdx.x * 4 + (threadIdx.x >> 6);
    const int nw = gridDim.x * 4;
    for (int c = wv; c < n; c += nw) {
        float acc = b2f(y[(size_t)c * 64 + lane]);      // self-loop term
        int beg = offs[c], num = cnt[c];
        int p = 0;
        for (; p + 4 <= num; p += 4) {                   // 4 outstanding 128B gathers
            int r0 = csr[beg + p],     r1 = csr[beg + p + 1];
            int r2 = csr[beg + p + 2], r3 = csr[beg + p + 3];
            float a0 = b2f(y[(size_t)r0 * 64 + lane]);
            float a1 = b2f(y[(size_t)r1 * 64 + lane]);
            float a2 = b2f(y[(size_t)r2 * 64 + lane]);
            float a3 = b2f(y[(size_t)r3 * 64 + lane]);
            acc += (a0 + a1) + (a2 + a3);
        }
        for (; p < num; ++p) acc += b2f(y[(size_t)csr[beg + p] * 64 + lane]);
        xl[(size_t)c * 64 + lane] = f2b(fmaxf(acc * dinv[c], 0.0f));
    }
}

// ---------------- prep: W1^T in bf16, padded [64][KP], rows k>=144 zero -------------
__global__ __launch_bounds__(256) void prep_kernel(const float* __restrict__ w1,
                                                   unsigned short* __restrict__ w1t)
{
    int i = blockIdx.x * 256 + threadIdx.x;
    if (i < 64 * KP) {
        int n = i / KP, k = i - n * KP;
        float v = (k < 144) ? w1[k * 64 + n] : 0.f;
        w1t[i] = f2b(v);
    }
}

// ---------------- edge MLP via bf16 MFMA: 64 edges/block, 4 waves -------------------
__global__ __launch_bounds__(256) void mlp_kernel(
    const unsigned short* __restrict__ xl, const int* __restrict__ ei,
    const float* __restrict__ ea, const unsigned short* __restrict__ w1t,
    const float* __restrict__ b1, const float* __restrict__ w2,
    const float* __restrict__ b2, float* __restrict__ out)
{
    __shared__ unsigned short As[64 * KP];   // edge_in tile, bf16
    __shared__ unsigned short Bs[64 * KP];   // W1^T, bf16
    const int t = threadIdx.x;
    const int base = blockIdx.x * 64;

    // stage W1^T (pre-converted, linear copy, conflict-free b128 writes)
    {
        const uint4* s = (const uint4*)w1t;
        uint4* d = (uint4*)Bs;
        #pragma unroll
        for (int it = 0; it < 6; ++it) {
            int i = t + it * 256;
            if (i < (64 * KP) / 8) d[i] = s[i];
        }
    }
    // stage h_src (cols 0..63) and h_dst (cols 64..127), bf16 rows of xl (128 B each)
    #pragma unroll
    for (int it = 0; it < 4; ++it) {
        int i = t + it * 256;                // 1024 (e,chunk) pairs
        int e = i >> 4, c = i & 15;
        int src = ei[base + e];
        *(uint2*)&As[e * KP + c * 4] = *(const uint2*)&xl[(size_t)src * 64 + c * 4];
    }
    #pragma unroll
    for (int it = 0; it < 4; ++it) {
        int i = t + it * 256;
        int e = i >> 4, c = i & 15;
        int dst = ei[N_EDGES + base + e];
        *(uint2*)&As[e * KP + 64 + c * 4] = *(const uint2*)&xl[(size_t)dst * 64 + c * 4];
    }
    // stage edge_attr (cols 128..143, fp32->bf16) + zero pad (cols 144..159)
    {
        int e = t >> 2, c = t & 3;
        float4 v = *(const float4*)&ea[(size_t)(base + e) * 16 + c * 4];
        ushort4 b;
        b.x = f2b(v.x); b.y = f2b(v.y); b.z = f2b(v.z); b.w = f2b(v.w);
        *(ushort4*)&As[e * KP + 128 + c * 4] = b;
        uint2 z; z.x = 0; z.y = 0;
        *(uint2*)&As[e * KP + 144 + c * 4] = z;
    }
    __syncthreads();

    const int lane = t & 63, w = t >> 6;
    const int col0 = lane & 15, rgrp = lane >> 4;
    const int arow = w * 16 + col0;

    f32x4 acc[4];
    #pragma unroll
    for (int nt = 0; nt < 4; ++nt) acc[nt] = (f32x4){0.f, 0.f, 0.f, 0.f};

    #pragma unroll
    for (int ks = 0; ks < KU / 32; ++ks) {
        int klane = ks * 32 + rgrp * 8;
        bf16x8 a = *(const bf16x8*)&As[arow * KP + klane];
        #pragma unroll
        for (int nt = 0; nt < 4; ++nt) {
            bf16x8 bfr = *(const bf16x8*)&Bs[(nt * 16 + col0) * KP + klane];
            acc[nt] = __builtin_amdgcn_mfma_f32_16x16x32_bf16(a, bfr, acc[nt], 0, 0, 0);
        }
    }

    // epilogue: hid = relu(acc + b1), logit = hid @ w2 + b2
    // C layout: col = lane&15 (per nt tile), row = (lane>>4)*4 + j
    float bsum = b2[0];
    float part[4];
    #pragma unroll
    for (int j = 0; j < 4; ++j) {
        float s = 0.f;
        #pragma unroll
        for (int nt = 0; nt < 4; ++nt) {
            int nn = nt * 16 + col0;
            s += fmaxf(acc[nt][j] + b1[nn], 0.f) * w2[nn];
        }
        #pragma unroll
        for (int m = 1; m < 16; m <<= 1) s += __shfl_xor(s, m, 64);
        part[j] = s;
    }
    if (col0 == 0) {
        int row = rgrp * 4;
        #pragma unroll
        for (int j = 0; j < 4; ++j)
            out[base + w * 16 + row + j] = part[j] + bsum;
    }
}

extern "C" void kernel_launch(void* const* d_in, const int* in_sizes, int n_in,
                              void* d_out, int out_size, void* d_ws, size_t ws_size,
                              hipStream_t stream)
{
    const float* xs     = (const float*)d_in[0];
    const int*   ei     = (const int*)  d_in[1];
    const float* ea     = (const float*)d_in[2];
    const float* init_w = (const float*)d_in[3];
    const float* w_ih   = (const float*)d_in[4];
    const float* w_hh   = (const float*)d_in[5];
    const float* b_ih   = (const float*)d_in[6];
    const float* b_hh   = (const float*)d_in[7];
    const float* w1     = (const float*)d_in[8];
    const float* b1     = (const float*)d_in[9];
    const float* w2     = (const float*)d_in[10];
    const float* b2     = (const float*)d_in[11];
    float* out = (float*)d_out;

    char* ws = (char*)d_ws;
    size_t off = 0;
    auto alloc = [&](size_t bytes) {
        void* p = ws + off;
        off = (off + bytes + 255) & ~(size_t)255;
        return p;
    };
    float*          h5   = (float*)alloc(64 * 64 * sizeof(float));
    int*            deg  = (int*)  alloc((size_t)N_NODES * sizeof(int));
    int*            fill = (int*)  alloc((size_t)N_NODES * sizeof(int));
    float*          dinv = (float*)alloc((size_t)N_NODES * sizeof(float));
    int*            offs = (int*)  alloc((size_t)N_NODES * sizeof(int));
    int*            csr  = (int*)  alloc((size_t)N_EDGES * sizeof(int));
    unsigned short* y    = (unsigned short*)alloc((size_t)N_NODES * 64 * sizeof(unsigned short));
    unsigned short* xl   = (unsigned short*)alloc((size_t)N_NODES * 64 * sizeof(unsigned short));
    unsigned short* w1t  = (unsigned short*)alloc((size_t)64 * KP * sizeof(unsigned short));

    hipMemsetAsync(deg, 0, (size_t)N_NODES * sizeof(int), stream);
    hipMemsetAsync(fill, 0, (size_t)N_NODES * sizeof(int), stream);

    lstm_kernel<<<64, 256, 0, stream>>>(init_w, w_ih, w_hh, b_ih, b_hh, h5);
    prep_kernel<<<(64 * KP + 255) / 256, 256, 0, stream>>>(w1, w1t);
    deg_kernel<<<1024, 256, 0, stream>>>(ei + N_EDGES, deg, N_EDGES);
    dinv_kernel<<<512, 256, 0, stream>>>(deg, dinv, N_NODES);
    scan_kernel<<<1, 1024, 0, stream>>>(deg, offs, N_NODES);
    fill_kernel<<<1024, 256, 0, stream>>>(ei, ei + N_EDGES, offs, fill, csr, N_EDGES);

    const float* x4 = xs + (size_t)4 * N_NODES * 64;
    xw_kernel<<<2048, 256, 0, stream>>>(x4, h5, dinv, y, N_NODES);
    gather_kernel<<<2048, 256, 0, stream>>>(offs, deg, csr, y, dinv, xl, N_NODES);
    mlp_kernel<<<N_EDGES / 64, 256, 0, stream>>>(xl, ei, ea, w1t, b1, w2, b2, out);
}

// Round 3
// 666.550 us; speedup vs baseline: 1.7793x; 1.0387x over previous
//
#include <hip/hip_runtime.h>
#include <hip/hip_bf16.h>
#include <math.h>

#define N_NODES 100000
#define N_EDGES 1600000
#define NCHUNK 98            // ceil(100000/1024)

typedef __attribute__((ext_vector_type(8))) short bf16x8;
typedef __attribute__((ext_vector_type(4))) float f32x4;

__device__ __forceinline__ float sigmoidf_(float x) { return 1.0f / (1.0f + expf(-x)); }
__device__ __forceinline__ unsigned short f2b(float x) {
    __hip_bfloat16 b = __float2bfloat16(x);
    return *(unsigned short*)&b;
}
__device__ __forceinline__ float b2f(unsigned short u) {
    __hip_bfloat16 b = *(__hip_bfloat16*)&u;
    return __bfloat162float(b);
}

// ---------------- LSTM: 64 independent row-recurrences, 5 steps ----------------
__global__ __launch_bounds__(256) void lstm_kernel(
    const float* __restrict__ init_w, const float* __restrict__ w_ih,
    const float* __restrict__ w_hh, const float* __restrict__ b_ih,
    const float* __restrict__ b_hh, float* __restrict__ h_out)
{
    __shared__ float wsum[256 * 65];
    __shared__ float hst[64];
    __shared__ float cst[64];
    __shared__ float gts[256];
    const int t = threadIdx.x;
    const int r = blockIdx.x;

    for (int i = t; i < 256 * 64; i += 256) {
        int g = i >> 6, k = i & 63;
        wsum[g * 65 + k] = w_ih[i] + w_hh[i];
    }
    if (t < 64) hst[t] = init_w[t * 64 + r];
    __syncthreads();

    {
        float acc = b_ih[t] + b_hh[t];
        for (int k = 0; k < 64; ++k) acc += hst[k] * w_ih[t * 64 + k];
        gts[t] = acc;
    }
    __syncthreads();
    if (t < 64) {
        float ig = sigmoidf_(gts[t]);
        float gg = tanhf(gts[128 + t]);
        float og = sigmoidf_(gts[192 + t]);
        float c = ig * gg;
        float h = og * tanhf(c);
        cst[t] = c; hst[t] = h;
    }
    __syncthreads();

    for (int step = 1; step < 5; ++step) {
        float acc = b_ih[t] + b_hh[t];
        for (int k = 0; k < 64; ++k) acc += hst[k] * wsum[t * 65 + k];
        gts[t] = acc;
        __syncthreads();
        if (t < 64) {
            float ig = sigmoidf_(gts[t]);
            float fg = sigmoidf_(gts[64 + t]);
            float gg = tanhf(gts[128 + t]);
            float og = sigmoidf_(gts[192 + t]);
            float c = fg * cst[t] + ig * gg;
            float h = og * tanhf(c);
            cst[t] = c; hst[t] = h;
        }
        __syncthreads();
    }
    if (t < 64) h_out[r * 64 + t] = hst[t];
}

// ---------------- degree count over col (int4-vectorized) ----------------
__global__ void deg_kernel(const int* __restrict__ col, int* __restrict__ cnt, int nE4)
{
    int i = blockIdx.x * blockDim.x + threadIdx.x;
    int stride = gridDim.x * blockDim.x;
    for (; i < nE4; i += stride) {
        int4 c = ((const int4*)col)[i];
        atomicAdd(&cnt[c.x], 1);
        atomicAdd(&cnt[c.y], 1);
        atomicAdd(&cnt[c.z], 1);
        atomicAdd(&cnt[c.w], 1);
    }
}

// ---------------- scan phase A: per-1024-chunk sums + dinv ----------------
__global__ __launch_bounds__(256) void scanA_kernel(
    const int* __restrict__ deg, int* __restrict__ partial,
    float* __restrict__ dinv, int n)
{
    __shared__ int wsums[4];
    const int t = threadIdx.x, lane = t & 63, wid = t >> 6;
    int i0 = blockIdx.x * 1024 + t * 4;
    int v0 = 0, v1 = 0, v2 = 0, v3 = 0;
    if (i0 + 3 < n) { int4 v = *(const int4*)(deg + i0); v0 = v.x; v1 = v.y; v2 = v.z; v3 = v.w; }
    else {
        if (i0 < n)     v0 = deg[i0];
        if (i0 + 1 < n) v1 = deg[i0 + 1];
        if (i0 + 2 < n) v2 = deg[i0 + 2];
        if (i0 + 3 < n) v3 = deg[i0 + 3];
    }
    if (i0 < n)     dinv[i0]     = rsqrtf((float)(v0 + 1));
    if (i0 + 1 < n) dinv[i0 + 1] = rsqrtf((float)(v1 + 1));
    if (i0 + 2 < n) dinv[i0 + 2] = rsqrtf((float)(v2 + 1));
    if (i0 + 3 < n) dinv[i0 + 3] = rsqrtf((float)(v3 + 1));
    int s = v0 + v1 + v2 + v3;
    #pragma unroll
    for (int m = 1; m < 64; m <<= 1) s += __shfl_xor(s, m, 64);
    if (lane == 0) wsums[wid] = s;
    __syncthreads();
    if (t == 0) partial[blockIdx.x] = wsums[0] + wsums[1] + wsums[2] + wsums[3];
}

// ---------------- scan phase B: exclusive scan of NCHUNK partials ----------------
__global__ void scanB_kernel(int* __restrict__ partial, int nb)
{
    __shared__ int w0;
    const int t = threadIdx.x, lane = t & 63, wid = t >> 6;
    int v = (t < nb) ? partial[t] : 0;
    int s = v;
    #pragma unroll
    for (int d = 1; d < 64; d <<= 1) { int u = __shfl_up(s, d, 64); if (lane >= d) s += u; }
    if (t == 63) w0 = s;
    __syncthreads();
    int ex = s - v + ((wid == 1) ? w0 : 0);
    if (t < nb) partial[t] = ex;
}

// ---------------- scan phase C: per-chunk exclusive scan + base; offs & fill ------
__global__ __launch_bounds__(256) void scanC_kernel(
    const int* __restrict__ deg, const int* __restrict__ partial,
    int* __restrict__ offs, int* __restrict__ fill, int n)
{
    __shared__ int wsums[4];
    const int t = threadIdx.x, lane = t & 63, wid = t >> 6;
    int i0 = blockIdx.x * 1024 + t * 4;
    int v0 = 0, v1 = 0, v2 = 0, v3 = 0;
    if (i0 + 3 < n) { int4 v = *(const int4*)(deg + i0); v0 = v.x; v1 = v.y; v2 = v.z; v3 = v.w; }
    else {
        if (i0 < n)     v0 = deg[i0];
        if (i0 + 1 < n) v1 = deg[i0 + 1];
        if (i0 + 2 < n) v2 = deg[i0 + 2];
        if (i0 + 3 < n) v3 = deg[i0 + 3];
    }
    int tot = v0 + v1 + v2 + v3;
    int s = tot;
    #pragma unroll
    for (int d = 1; d < 64; d <<= 1) { int u = __shfl_up(s, d, 64); if (lane >= d) s += u; }
    if (lane == 63) wsums[wid] = s;
    __syncthreads();
    if (t == 0) { int run = 0; for (int w = 0; w < 4; ++w) { int u = wsums[w]; wsums[w] = run; run += u; } }
    __syncthreads();
    int ex = s - tot + wsums[wid] + partial[blockIdx.x];
    if (i0 < n)     { offs[i0]     = ex;                fill[i0]     = ex; }
    if (i0 + 1 < n) { offs[i0 + 1] = ex + v0;           fill[i0 + 1] = ex + v0; }
    if (i0 + 2 < n) { offs[i0 + 2] = ex + v0 + v1;      fill[i0 + 2] = ex + v0 + v1; }
    if (i0 + 3 < n) { offs[i0 + 3] = ex + v0 + v1 + v2; fill[i0 + 3] = ex + v0 + v1 + v2; }
}

// ---------------- CSR fill (fill[] pre-initialized to offs[]) ----------------
__global__ void fill_kernel(const int* __restrict__ row, const int* __restrict__ col,
                            int* __restrict__ fill, int* __restrict__ csr, int nE4)
{
    int i = blockIdx.x * blockDim.x + threadIdx.x;
    int stride = gridDim.x * blockDim.x;
    for (; i < nE4; i += stride) {
        int4 c = ((const int4*)col)[i];
        int4 r = ((const int4*)row)[i];
        csr[atomicAdd(&fill[c.x], 1)] = r.x;
        csr[atomicAdd(&fill[c.y], 1)] = r.y;
        csr[atomicAdd(&fill[c.z], 1)] = r.z;
        csr[atomicAdd(&fill[c.w], 1)] = r.w;
    }
}

// ---------------- y[n][j] = dinv[n] * sum_k x4[n][k] * h5[j][k]  (bf16 out) --------
__global__ __launch_bounds__(256) void xw_kernel(
    const float* __restrict__ x4, const float* __restrict__ h5,
    const float* __restrict__ dinv, unsigned short* __restrict__ y, int n)
{
    __shared__ float wlds[64 * 64];          // wlds[k][j] = h5[j][k]
    const int t = threadIdx.x;
    for (int i = t; i < 4096; i += 256) {
        int j = i >> 6, k = i & 63;
        wlds[k * 64 + j] = h5[i];
    }
    __syncthreads();
    const int lane = t & 63;
    int wv = blockIdx.x * 4 + (t >> 6);
    const int nw = gridDim.x * 4;
    for (int nd = wv; nd < n; nd += nw) {
        float xv = x4[(size_t)nd * 64 + lane];
        float acc = 0.f;
        #pragma unroll
        for (int k = 0; k < 64; ++k) {
            float xk = __shfl(xv, k, 64);
            acc += xk * wlds[k * 64 + lane];
        }
        y[(size_t)nd * 64 + lane] = f2b(acc * dinv[nd]);
    }
}

// ---------------- gather: 4 edges in flight per wave, 16 lanes x 8B per row --------
__global__ __launch_bounds__(256) void gather_kernel(
    const int* __restrict__ offs, const int* __restrict__ cnt,
    const int* __restrict__ csr, const unsigned short* __restrict__ y,
    const float* __restrict__ dinv, unsigned short* __restrict__ xl, int n)
{
    const int lane = threadIdx.x & 63;
    const int sub = lane >> 4, q = lane & 15;
    int wv = (blockIdx.x * 256 + threadIdx.x) >> 6;
    const int nw = (gridDim.x * 256) >> 6;
    for (int c = wv; c < n; c += nw) {
        const int beg = offs[c], num = cnt[c];
        float acc0 = 0.f, acc1 = 0.f, acc2 = 0.f, acc3 = 0.f;
        int p = sub;
        for (; p + 4 < num; p += 8) {                    // 2 edges per sub per iter
            int r0 = csr[beg + p];
            int r1 = csr[beg + p + 4];
            uint2 v0 = *(const uint2*)&y[(size_t)r0 * 64 + q * 4];
            uint2 v1 = *(const uint2*)&y[(size_t)r1 * 64 + q * 4];
            acc0 += b2f((unsigned short)(v0.x & 0xffff)) + b2f((unsigned short)(v1.x & 0xffff));
            acc1 += b2f((unsigned short)(v0.x >> 16))    + b2f((unsigned short)(v1.x >> 16));
            acc2 += b2f((unsigned short)(v0.y & 0xffff)) + b2f((unsigned short)(v1.y & 0xffff));
            acc3 += b2f((unsigned short)(v0.y >> 16))    + b2f((unsigned short)(v1.y >> 16));
        }
        if (p < num) {
            int r0 = csr[beg + p];
            uint2 v0 = *(const uint2*)&y[(size_t)r0 * 64 + q * 4];
            acc0 += b2f((unsigned short)(v0.x & 0xffff));
            acc1 += b2f((unsigned short)(v0.x >> 16));
            acc2 += b2f((unsigned short)(v0.y & 0xffff));
            acc3 += b2f((unsigned short)(v0.y >> 16));
        }
        acc0 += __shfl_xor(acc0, 16, 64); acc0 += __shfl_xor(acc0, 32, 64);
        acc1 += __shfl_xor(acc1, 16, 64); acc1 += __shfl_xor(acc1, 32, 64);
        acc2 += __shfl_xor(acc2, 16, 64); acc2 += __shfl_xor(acc2, 32, 64);
        acc3 += __shfl_xor(acc3, 16, 64); acc3 += __shfl_xor(acc3, 32, 64);
        if (sub == 0) {
            uint2 sv = *(const uint2*)&y[(size_t)c * 64 + q * 4];   // self-loop row
            float d = dinv[c];
            ushort4 st;
            st.x = f2b(fmaxf((acc0 + b2f((unsigned short)(sv.x & 0xffff))) * d, 0.f));
            st.y = f2b(fmaxf((acc1 + b2f((unsigned short)(sv.x >> 16)))    * d, 0.f));
            st.z = f2b(fmaxf((acc2 + b2f((unsigned short)(sv.y & 0xffff))) * d, 0.f));
            st.w = f2b(fmaxf((acc3 + b2f((unsigned short)(sv.y >> 16)))    * d, 0.f));
            *(ushort4*)&xl[(size_t)c * 64 + q * 4] = st;
        }
    }
}

// ---------------- prep: W1^T in bf16, [64][160], cols k>=144 zero ----------------
__global__ __launch_bounds__(256) void prep_kernel(const float* __restrict__ w1,
                                                   unsigned short* __restrict__ w1t)
{
    int i = blockIdx.x * 256 + threadIdx.x;
    if (i < 64 * 160) {
        int n = i / 160, k = i - n * 160;
        float v = (k < 144) ? w1[k * 64 + n] : 0.f;
        w1t[i] = f2b(v);
    }
}

// ---------------- edge MLP: LDS-free, B in registers, 16 edges/wave/tile -----------
__global__ __launch_bounds__(256) void mlp_kernel(
    const unsigned short* __restrict__ xl, const int* __restrict__ ei,
    const float* __restrict__ ea, const unsigned short* __restrict__ w1t,
    const float* __restrict__ b1, const float* __restrict__ w2,
    const float* __restrict__ b2, float* __restrict__ out)
{
    const int t = threadIdx.x;
    const int lane = t & 63;
    const int col0 = lane & 15, rgrp = lane >> 4;
    const int gw = (blockIdx.x * 256 + t) >> 6;
    const int nw = (gridDim.x * 256) >> 6;

    // W1^T fragments, held in registers (L1-resident source, loaded once per wave)
    bf16x8 bfr[5][4];
    #pragma unroll
    for (int ks = 0; ks < 5; ++ks)
        #pragma unroll
        for (int nt = 0; nt < 4; ++nt)
            bfr[ks][nt] = *(const bf16x8*)&w1t[(nt * 16 + col0) * 160 + ks * 32 + rgrp * 8];

    float b1v[4], w2v[4];
    #pragma unroll
    for (int nt = 0; nt < 4; ++nt) {
        b1v[nt] = b1[nt * 16 + col0];
        w2v[nt] = w2[nt * 16 + col0];
    }
    const float b2s = b2[0];
    const bf16x8 zv = {0, 0, 0, 0, 0, 0, 0, 0};

    for (int tile = gw; tile < N_EDGES / 16; tile += nw) {
        const int e0 = tile * 16;
        const int eidx = e0 + col0;
        const int src = ei[eidx];
        const int dst = ei[N_EDGES + eidx];
        const unsigned short* ps = xl + (size_t)src * 64 + rgrp * 8;
        const unsigned short* pd = xl + (size_t)dst * 64 + rgrp * 8;
        bf16x8 av[5];
        av[0] = *(const bf16x8*)ps;
        av[1] = *(const bf16x8*)(ps + 32);
        av[2] = *(const bf16x8*)pd;
        av[3] = *(const bf16x8*)(pd + 32);
        if (rgrp < 2) {
            const float* pe = ea + (size_t)eidx * 16 + rgrp * 8;
            float4 u0 = *(const float4*)pe;
            float4 u1 = *(const float4*)(pe + 4);
            union { bf16x8 v; unsigned short u[8]; } au;
            au.u[0] = f2b(u0.x); au.u[1] = f2b(u0.y); au.u[2] = f2b(u0.z); au.u[3] = f2b(u0.w);
            au.u[4] = f2b(u1.x); au.u[5] = f2b(u1.y); au.u[6] = f2b(u1.z); au.u[7] = f2b(u1.w);
            av[4] = au.v;
        } else {
            av[4] = zv;             // K-pad rows 144..159
        }

        f32x4 acc[4];
        #pragma unroll
        for (int nt = 0; nt < 4; ++nt) acc[nt] = (f32x4){0.f, 0.f, 0.f, 0.f};
        #pragma unroll
        for (int ks = 0; ks < 5; ++ks)
            #pragma unroll
            for (int nt = 0; nt < 4; ++nt)
                acc[nt] = __builtin_amdgcn_mfma_f32_16x16x32_bf16(av[ks], bfr[ks][nt], acc[nt], 0, 0, 0);

        // epilogue: logit = relu(acc + b1) . w2 + b2 ; C: col=lane&15, row=rgrp*4+j
        float part[4];
        #pragma unroll
        for (int j = 0; j < 4; ++j) {
            float s = 0.f;
            #pragma unroll
            for (int nt = 0; nt < 4; ++nt)
                s += fmaxf(acc[nt][j] + b1v[nt], 0.f) * w2v[nt];
            #pragma unroll
            for (int m = 1; m < 16; m <<= 1) s += __shfl_xor(s, m, 64);
            part[j] = s;
        }
        if (col0 == 0) {
            float4 o;
            o.x = part[0] + b2s; o.y = part[1] + b2s;
            o.z = part[2] + b2s; o.w = part[3] + b2s;
            *(float4*)&out[e0 + rgrp * 4] = o;
        }
    }
}

extern "C" void kernel_launch(void* const* d_in, const int* in_sizes, int n_in,
                              void* d_out, int out_size, void* d_ws, size_t ws_size,
                              hipStream_t stream)
{
    const float* xs     = (const float*)d_in[0];
    const int*   ei     = (const int*)  d_in[1];
    const float* ea     = (const float*)d_in[2];
    const float* init_w = (const float*)d_in[3];
    const float* w_ih   = (const float*)d_in[4];
    const float* w_hh   = (const float*)d_in[5];
    const float* b_ih   = (const float*)d_in[6];
    const float* b_hh   = (const float*)d_in[7];
    const float* w1     = (const float*)d_in[8];
    const float* b1     = (const float*)d_in[9];
    const float* w2     = (const float*)d_in[10];
    const float* b2     = (const float*)d_in[11];
    float* out = (float*)d_out;

    char* ws = (char*)d_ws;
    size_t off = 0;
    auto alloc = [&](size_t bytes) {
        void* p = ws + off;
        off = (off + bytes + 255) & ~(size_t)255;
        return p;
    };
    float*          h5      = (float*)alloc(64 * 64 * sizeof(float));
    int*            deg     = (int*)  alloc((size_t)N_NODES * sizeof(int));
    int*            fill    = (int*)  alloc((size_t)N_NODES * sizeof(int));
    float*          dinv    = (float*)alloc((size_t)N_NODES * sizeof(float));
    int*            offs    = (int*)  alloc((size_t)N_NODES * sizeof(int));
    int*            csr     = (int*)  alloc((size_t)N_EDGES * sizeof(int));
    unsigned short* y       = (unsigned short*)alloc((size_t)N_NODES * 64 * sizeof(unsigned short));
    unsigned short* xl      = (unsigned short*)alloc((size_t)N_NODES * 64 * sizeof(unsigned short));
    unsigned short* w1t     = (unsigned short*)alloc((size_t)64 * 160 * sizeof(unsigned short));
    int*            partial = (int*)  alloc(128 * sizeof(int));

    hipMemsetAsync(deg, 0, (size_t)N_NODES * sizeof(int), stream);

    lstm_kernel<<<64, 256, 0, stream>>>(init_w, w_ih, w_hh, b_ih, b_hh, h5);
    prep_kernel<<<(64 * 160 + 255) / 256, 256, 0, stream>>>(w1, w1t);
    deg_kernel<<<1024, 256, 0, stream>>>(ei + N_EDGES, deg, N_EDGES / 4);
    scanA_kernel<<<NCHUNK, 256, 0, stream>>>(deg, partial, dinv, N_NODES);
    scanB_kernel<<<1, 128, 0, stream>>>(partial, NCHUNK);
    scanC_kernel<<<NCHUNK, 256, 0, stream>>>(deg, partial, offs, fill, N_NODES);
    fill_kernel<<<1024, 256, 0, stream>>>(ei, ei + N_EDGES, fill, csr, N_EDGES / 4);

    const float* x4 = xs + (size_t)4 * N_NODES * 64;
    xw_kernel<<<2048, 256, 0, stream>>>(x4, h5, dinv, y, N_NODES);
    gather_kernel<<<2048, 256, 0, stream>>>(offs, deg, csr, y, dinv, xl, N_NODES);
    mlp_kernel<<<2048, 256, 0, stream>>>(xl, ei, ea, w1t, b1, w2, b2, out);
}